// Round 1
// 890.245 us; speedup vs baseline: 1.0678x; 1.0678x over previous
//
#include <hip/hip_runtime.h>

// CRF backward decode, round 2: warp-per-chain with dense row streaming.
//
// Key idea: the address of row bp[t,b,:] is state-INDEPENDENT — only the
// 4B selection within the row depends on s_t. So stream rows densely
// (coalesced int2/lane, prefetchable, BW-bound) and do the dependent
// gather s' = row[s] as a cross-lane __shfl (ds_bpermute, ~50 cyc) instead
// of a ~900-cyc HBM miss. States are logged to LDS (1B each); the tags
// gather runs as a fully parallel epilogue off the critical path.
//
// Roofline: 512 MiB bp dense + ~64 MiB tags sparse + 4 MiB out ≈ 92 µs
// at 6.3 TB/s achievable. Chain latency (~5 µs/wave serial) hidden by
// 16 waves/CU.

#define T_STEPS 256
#define BATCH   4096
#define NTAGS   128
#define WSZ     64
#define WARPS   4                  // warps (chains) per block
#define NBLOCKS (BATCH / WARPS)    // 1024 blocks x 256 threads

__global__ __launch_bounds__(256) void crf_warp_chain(
    const float* __restrict__ tags,   // (T, B, NTAGS) f32
    const int*   __restrict__ bp,     // (T, B, NTAGS) i32 in [0,128)
    const int*   __restrict__ init,   // (B,) i32
    float*       __restrict__ out)    // (T, B, 1) f32
{
    __shared__ unsigned char sstate[WARPS][T_STEPS];     // 1 KiB: state log
    __shared__ float         vbuf[WARPS][T_STEPS + 1];   // +1 pad -> conflict-free transpose

    const int tid  = threadIdx.x;
    const int lane = tid & (WSZ - 1);
    const int w    = tid >> 6;
    const int b    = blockIdx.x * WARPS + w;

    const size_t stride_t = (size_t)BATCH * NTAGS;   // elems per time step
    const size_t row_b    = (size_t)b * NTAGS;

    // Per-lane pointer into this chain's bp row: 64 lanes x int2 = 128 tags.
    const int2*  rp      = reinterpret_cast<const int2*>(bp + row_b) + lane;
    const size_t rp_step = stride_t / 2;             // int2 elems per t step

    int s = init[b];                                  // warp-uniform state

    int2 r = *rp;                                     // row 0
    rp += rp_step;

    // Chain: 255 updates. Row t+1 prefetches while row t's shuffle resolves.
    #pragma unroll 4
    for (int t = 0; t < T_STEPS - 1; ++t) {
        const int2 rn = *rp;                          // row t+1 (<= 255, in bounds)
        rp += rp_step;

        if (lane == 0) sstate[w][t] = (unsigned char)s;   // log s_t (pre-update)

        // s' = row[s]: element s lives in lane s>>1, component s&1.
        const int src = s >> 1;
        const int lo  = __shfl(r.x, src, WSZ);
        const int hi  = __shfl(r.y, src, WSZ);
        s = (s & 1) ? hi : lo;
        r = rn;
    }
    if (lane == 0) sstate[w][T_STEPS - 1] = (unsigned char)s;

    __syncthreads();   // make state log visible + order LDS phases

    // Parallel tags gather: lane l handles t = l, l+64, l+128, l+192.
    // 256 independent scattered 4B loads per warp — pure MLP, no chain.
    #pragma unroll
    for (int j = 0; j < T_STEPS / WSZ; ++j) {
        const int t  = lane + WSZ * j;
        const int st = (int)sstate[w][t];
        vbuf[w][t] = tags[(size_t)t * stride_t + row_b + (size_t)st];
    }

    __syncthreads();

    // Transposed write-out: consecutive tids cover 4 consecutive b at each t
    // -> 16B contiguous segments instead of lone 4B scatters.
    const int b0 = blockIdx.x * WARPS;
    #pragma unroll
    for (int k = 0; k < (T_STEPS * WARPS) / 256; ++k) {
        const int idx = k * 256 + tid;
        const int t   = idx >> 2;
        const int bl  = idx & 3;
        out[(size_t)t * BATCH + (size_t)(b0 + bl)] = vbuf[bl][t];
    }
}

extern "C" void kernel_launch(void* const* d_in, const int* in_sizes, int n_in,
                              void* d_out, int out_size, void* d_ws, size_t ws_size,
                              hipStream_t stream) {
    const float* tags = (const float*)d_in[0];
    const int*   bp   = (const int*)d_in[1];
    const int*   init = (const int*)d_in[2];
    float*       out  = (float*)d_out;

    crf_warp_chain<<<dim3(NBLOCKS), dim3(256), 0, stream>>>(tags, bp, init, out);
}